// Round 7
// baseline (322.609 us; speedup 1.0000x reference)
//
#include <hip/hip_runtime.h>

#define T256 256
#define SB 1024
#define BIG 1024
#define RANGE 12500
#define ITEMS 8   // SB*ITEMS = 8192 elements per scan1 block (g>>13 in scan3)

// ================= atomic-free path =================

// per-block LDS-privatized histogram (col) + weighted histogram (row)
__global__ void __launch_bounds__(BIG)
histdeg_kernel(const int* __restrict__ row, const int* __restrict__ col,
               const float* __restrict__ w, int* __restrict__ H,
               float* __restrict__ degH, int E, int N, int chunk, int nR) {
  __shared__ int sc[RANGE];
  __shared__ float sd[RANGE];
  int b = blockIdx.x;
  long base = (long)b * chunk;
  int cnt = (int)min((long)chunk, (long)E - base);
  if (cnt < 0) cnt = 0;
  int t = threadIdx.x;
  for (int p = 0; p < nR; p++) {
    int lo = p * RANGE;
    int hi = min(lo + RANGE, N);
    int len = hi - lo;
    for (int i = t; i < len; i += BIG) { sc[i] = 0; sd[i] = 0.f; }
    __syncthreads();
    for (int i = t; i < cnt; i += BIG) {
      long e = base + i;
      int c = col[e], r = row[e];
      if (c >= lo && c < hi) atomicAdd(&sc[c - lo], 1);        // LDS atomic
      if (r >= lo && r < hi) atomicAdd(&sd[r - lo], w[e]);     // LDS atomic
    }
    __syncthreads();
    for (int i = t; i < len; i += BIG) {
      H[(long)b * N + lo + i] = sc[i];
      degH[(long)b * N + lo + i] = sd[i];
    }
    __syncthreads();
  }
}

// stage 1: scan 8192 elements/block in (bin-major, block-minor) logical order
// logical g -> storage H[(g & bMask)*N + (g >> bShift)]
__global__ void __launch_bounds__(SB)
scan1_kernel(int* __restrict__ H, int* __restrict__ bsum, long n2, int N,
             int bMask, int bShift) {
  __shared__ int s[SB];
  int t = threadIdx.x;
  long g0 = (long)blockIdx.x * (SB * ITEMS) + (long)t * ITEMS;
  int v[ITEMS];
  int tot = 0;
#pragma unroll
  for (int k = 0; k < ITEMS; k++) {
    long g = g0 + k;
    int a = 0;
    if (g < n2) a = H[(long)(g & bMask) * N + (g >> bShift)];
    v[k] = a; tot += a;
  }
  s[t] = tot;
  __syncthreads();
  for (int d = 1; d < SB; d <<= 1) {
    int u = (t >= d) ? s[t - d] : 0;
    __syncthreads();
    s[t] += u;
    __syncthreads();
  }
  int run = s[t] - tot;   // exclusive thread base within block
#pragma unroll
  for (int k = 0; k < ITEMS; k++) {
    long g = g0 + k;
    if (g < n2) H[(long)(g & bMask) * N + (g >> bShift)] = run;
    run += v[k];
  }
  if (t == SB - 1) bsum[blockIdx.x] = s[SB - 1];
}

// stage 2: exclusive scan of block totals (nb <= 1024)
__global__ void __launch_bounds__(SB)
scan_top_kernel(int* __restrict__ bsum, int nb) {
  __shared__ int s[SB];
  int t = threadIdx.x;
  int v = (t < nb) ? bsum[t] : 0;
  s[t] = v;
  __syncthreads();
  for (int d = 1; d < SB; d <<= 1) {
    int u = (t >= d) ? s[t - d] : 0;
    __syncthreads();
    s[t] += u;
    __syncthreads();
  }
  if (t < nb) bsum[t] = s[t] - v;
}

// stage 3: add block offsets; fuse degH column-reduce -> disq
__global__ void scan3_kernel(int* __restrict__ H, const int* __restrict__ bsum,
                             const float* __restrict__ degH, float* __restrict__ disq,
                             long n2, int N, int nB, int bMask, int bShift) {
  long g = (long)blockIdx.x * blockDim.x + threadIdx.x;
  if (g < n2) H[(long)(g & bMask) * N + (g >> bShift)] += bsum[g >> 13];
  if (g < N) {
    float d = 0.f;
    for (int b = 0; b < nB; b++) d += degH[(long)b * N + g];
    disq[g] = (d > 0.f) ? rsqrtf(d) : 0.f;
  }
}

// block-exclusive scatter: LDS cursors from own scanned row, no global atomics
__global__ void __launch_bounds__(BIG)
bucket2_kernel(const int* __restrict__ row, const int* __restrict__ col,
               const float* __restrict__ w, const float* __restrict__ disq,
               const int* __restrict__ S, int2* __restrict__ pairs,
               int E, int N, int chunk, int nR) {
  __shared__ int cur[RANGE];
  int b = blockIdx.x;
  long base = (long)b * chunk;
  int cnt = (int)min((long)chunk, (long)E - base);
  if (cnt < 0) cnt = 0;
  int t = threadIdx.x;
  for (int p = 0; p < nR; p++) {
    int lo = p * RANGE;
    int hi = min(lo + RANGE, N);
    int len = hi - lo;
    for (int i = t; i < len; i += BIG) cur[i] = S[(long)b * N + lo + i];
    __syncthreads();
    for (int i = t; i < cnt; i += BIG) {
      long e = base + i;
      int c = col[e];
      if (c >= lo && c < hi) {
        int r = row[e];
        float nm = -w[e] * disq[r] * disq[c];
        int pos = atomicAdd(&cur[c - lo], 1);   // LDS atomic, exclusive range
        pairs[pos] = make_int2(r, __float_as_int(nm));
      }
    }
    __syncthreads();
  }
}

// ================= legacy fallback (device atomics) =================

__global__ void zero_kernel(int* __restrict__ p, long n) {
  long i = (long)blockIdx.x * blockDim.x + threadIdx.x;
  long stride = (long)gridDim.x * blockDim.x;
  for (; i < n; i += stride) p[i] = 0;
}

__global__ void deghist_dev_kernel(const float* __restrict__ w, const int* __restrict__ row,
                                   const int* __restrict__ col, float* __restrict__ deg,
                                   int* __restrict__ cntArr, int E) {
  int e = blockIdx.x * blockDim.x + threadIdx.x;
  if (e < E) {
    atomicAdd(&deg[row[e]], w[e]);
    atomicAdd(&cntArr[col[e]], 1);
  }
}

__global__ void bucket_dev_kernel(const float* __restrict__ w, const int* __restrict__ row,
                                  const int* __restrict__ col, const float* __restrict__ disq,
                                  int* __restrict__ off, int2* __restrict__ pairs, int E) {
  int e = blockIdx.x * blockDim.x + threadIdx.x;
  if (e >= E) return;
  int r = row[e], c = col[e];
  float v = -w[e] * disq[r] * disq[c];
  int p = atomicAdd(&off[c], 1);
  pairs[p] = make_int2(r, __float_as_int(v));
}

// ================= shared tail =================

// MODE 0: S[c] = start, end = S[c+1] (or E).  MODE 1: S[c] = end, start = S[c-1] (or 0).
template <int MODE>
__global__ void gather_kernel(const float* __restrict__ x, const int* __restrict__ S,
                              const int2* __restrict__ pairs, float* __restrict__ Tx,
                              int n, int E) {
  int wid = (int)(((long)blockIdx.x * blockDim.x + threadIdx.x) >> 6);
  if (wid >= n) return;
  int lane = threadIdx.x & 63;
  int slot = lane >> 3;
  int f4 = lane & 7;
  int start, end;
  if (MODE == 0) { start = S[wid]; end = (wid + 1 < n) ? S[wid + 1] : E; }
  else           { start = wid ? S[wid - 1] : 0; end = S[wid]; }
  float4 acc = make_float4(0.f, 0.f, 0.f, 0.f);
  for (int i = start + slot; i < end; i += 8) {
    int2 pv = pairs[i];
    float v = __int_as_float(pv.y);
    float4 xr = *(const float4*)(x + (long)pv.x * 32 + f4 * 4);
    acc.x += v * xr.x;
    acc.y += v * xr.y;
    acc.z += v * xr.z;
    acc.w += v * xr.w;
  }
#pragma unroll
  for (int d = 8; d < 64; d <<= 1) {
    acc.x += __shfl_xor(acc.x, d);
    acc.y += __shfl_xor(acc.y, d);
    acc.z += __shfl_xor(acc.z, d);
    acc.w += __shfl_xor(acc.w, d);
  }
  if (slot == 0) *(float4*)(Tx + (long)wid * 32 + f4 * 4) = acc;
}

__global__ void __launch_bounds__(T256, 2)
gate_kernel(const float* __restrict__ x, const float* __restrict__ Tx,
            const float* __restrict__ Wx0, const float* __restrict__ Wx1,
            const float* __restrict__ bx, const float* __restrict__ bh,
            const float* __restrict__ Wlin, const float* __restrict__ blin,
            float* __restrict__ out, int n) {
  int lane = threadIdx.x & 63;
  int wave = blockIdx.x * (T256 / 64) + (threadIdx.x >> 6);
  int nwaves = gridDim.x * (T256 / 64);

  float wz0[32], wz1[32], wt0[32], wt1[32];
#pragma unroll
  for (int f = 0; f < 32; f++) {
    wz0[f] = Wx0[f * 64 + lane];
    wz1[f] = Wx1[f * 64 + lane];
    wt0[f] = Wx0[4096 + f * 64 + lane];
    wt1[f] = Wx1[4096 + f * 64 + lane];
  }
  float bz = bx[lane] + bh[lane];
  float bt = bx[128 + lane] + bh[128 + lane];
  float wl = Wlin[lane];
  float bl = blin[0];

  for (int node = wave; node < n; node += nwaves) {
    const float4* xp = (const float4*)(x + (long)node * 32);
    const float4* tp = (const float4*)(Tx + (long)node * 32);
    float azx = 0.f, azt = 0.f, atx = 0.f, att = 0.f;
#pragma unroll
    for (int c = 0; c < 8; c++) {
      float4 xa = xp[c];
      float4 ta = tp[c];
      azx += xa.x * wz0[4 * c + 0];
      azx += xa.y * wz0[4 * c + 1];
      azx += xa.z * wz0[4 * c + 2];
      azx += xa.w * wz0[4 * c + 3];
      azt += ta.x * wz1[4 * c + 0];
      azt += ta.y * wz1[4 * c + 1];
      azt += ta.z * wz1[4 * c + 2];
      azt += ta.w * wz1[4 * c + 3];
      atx += xa.x * wt0[4 * c + 0];
      atx += xa.y * wt0[4 * c + 1];
      atx += xa.z * wt0[4 * c + 2];
      atx += xa.w * wt0[4 * c + 3];
      att += ta.x * wt1[4 * c + 0];
      att += ta.y * wt1[4 * c + 1];
      att += ta.z * wt1[4 * c + 2];
      att += ta.w * wt1[4 * c + 3];
    }
    float az = azx + azt + bz;
    float at = atx + att + bt;
    float zk = 1.0f / (1.0f + __expf(-az));
    float contrib = (1.0f - zk) * tanhf(at) * wl;
#pragma unroll
    for (int d = 1; d < 64; d <<= 1) contrib += __shfl_xor(contrib, d);
    if (lane == 0) out[node] = contrib + bl;
  }
}

extern "C" void kernel_launch(void* const* d_in, const int* in_sizes, int n_in,
                              void* d_out, int out_size, void* d_ws, size_t ws_size,
                              hipStream_t stream) {
  const float* x    = (const float*)d_in[0];
  const float* ew   = (const float*)d_in[1];
  const float* Wx0  = (const float*)d_in[2];
  const float* Wx1  = (const float*)d_in[3];
  const float* bx   = (const float*)d_in[4];
  const float* bh   = (const float*)d_in[7];
  const float* Wlin = (const float*)d_in[8];
  const float* blin = (const float*)d_in[9];
  const int*   ei   = (const int*)d_in[10];

  int N = in_sizes[0] / 32;
  int E = in_sizes[1];
  const int* row = ei;
  const int* col = ei + E;
  float* out = (float*)d_out;
  long tthreads = (long)N * 64;
  int nR = (N + RANGE - 1) / RANGE;

  // choose largest nB (power of 2) whose footprint fits:
  // [Tx 32N][disq N][H nB*N][degH∪pairs max(nB*N, 2E)][bsum 1024]
  int nB = 0, bShift = 0;
  size_t wTx = (size_t)N * 32, wH = 0, wRegion = 0, total = 0;
  for (int sh = 7; sh >= 3; sh--) {
    size_t cb = (size_t)1 << sh;
    size_t h = cb * N;
    size_t region = h > (size_t)2 * E ? h : (size_t)2 * E;
    size_t tot = wTx + N + h + region + 1024 + 2;
    if (tot * 4 <= ws_size) { nB = (int)cb; bShift = sh; wH = h; wRegion = region; total = tot; break; }
  }

  if (nB > 0) {
    float* Tx   = (float*)d_ws;
    float* disq = Tx + wTx;
    int*   H    = (int*)(disq + N);
    float* degH = (float*)(H + wH);            // aliased with pairs (degH dead first)
    int2*  pairs = (int2*)degH;
    int*   bsum = (int*)((float*)degH + wRegion);

    int chunk = (E + nB - 1) / nB;
    long n2 = (long)nB * N;
    int nb1 = (int)((n2 + SB * ITEMS - 1) / (SB * ITEMS));
    int bMask = nB - 1;

    histdeg_kernel<<<nB, BIG, 0, stream>>>(row, col, ew, H, degH, E, N, chunk, nR);
    scan1_kernel<<<nb1, SB, 0, stream>>>(H, bsum, n2, N, bMask, bShift);
    scan_top_kernel<<<1, SB, 0, stream>>>(bsum, nb1);
    scan3_kernel<<<(int)((n2 + T256 - 1) / T256), T256, 0, stream>>>(
        H, bsum, degH, disq, n2, N, nB, bMask, bShift);
    bucket2_kernel<<<nB, BIG, 0, stream>>>(row, col, ew, disq, H, pairs, E, N, chunk, nR);
    gather_kernel<0><<<(int)((tthreads + T256 - 1) / T256), T256, 0, stream>>>(
        x, H, pairs, Tx, N, E);
    gate_kernel<<<512, T256, 0, stream>>>(x, Tx, Wx0, Wx1, bx, bh, Wlin, blin, out, N);
  } else {
    // legacy: device-scope atomics, nB = 1 scan
    float* Tx   = (float*)d_ws;
    float* disq = Tx + wTx;
    int*   H    = (int*)(disq + N);            // N counts
    float* degH = (float*)(H + N);             // N deg
    int*   bsum = (int*)(degH + N);
    size_t head = wTx + N + N + N + 1024 + 2;
    if (head & 1) head++;
    int2* pairs = (int2*)((float*)d_ws + head);
    long n2 = N;
    int nb1 = (int)((n2 + SB * ITEMS - 1) / (SB * ITEMS));
    int eb = (E + T256 - 1) / T256;

    zero_kernel<<<256, T256, 0, stream>>>(H, N);
    zero_kernel<<<256, T256, 0, stream>>>((int*)degH, N);
    deghist_dev_kernel<<<eb, T256, 0, stream>>>(ew, row, col, degH, H, E);
    scan1_kernel<<<nb1, SB, 0, stream>>>(H, bsum, n2, N, 0, 0);
    scan_top_kernel<<<1, SB, 0, stream>>>(bsum, nb1);
    scan3_kernel<<<(int)((n2 + T256 - 1) / T256), T256, 0, stream>>>(
        H, bsum, degH, disq, n2, N, 1, 0, 0);
    bucket_dev_kernel<<<eb, T256, 0, stream>>>(ew, row, col, disq, H, pairs, E);
    gather_kernel<1><<<(int)((tthreads + T256 - 1) / T256), T256, 0, stream>>>(
        x, H, pairs, Tx, N, E);
    gate_kernel<<<512, T256, 0, stream>>>(x, Tx, Wx0, Wx1, bx, bh, Wlin, blin, out, N);
  }
}

// Round 8
// 173.852 us; speedup vs baseline: 1.8557x; 1.8557x over previous
//
#include <hip/hip_runtime.h>

#define T256 256
#define SB 1024
#define BIG 1024
#define RANGE_H 16700   // histdeg bins/pass: 16700*8B = 130.5 KiB LDS, 3 passes for N=50K
#define RANGE_B 25000   // bucket cursors/pass: 100 KB LDS, 2 passes
#define ITEMS 8         // scan1: 8192 elements per block (bsum index = g>>13)

// ================= atomic-free path =================

// grid (nB, nR): block (b,p) histograms chunk b over bin-range p. LDS-private, no global atomics.
__global__ void __launch_bounds__(BIG)
histdeg_kernel(const int* __restrict__ row, const int* __restrict__ col,
               const float* __restrict__ w, int* __restrict__ H,
               float* __restrict__ degH, int E, int N, int chunk) {
  __shared__ int sc[RANGE_H];
  __shared__ float sd[RANGE_H];
  int b = blockIdx.x;
  int lo = blockIdx.y * RANGE_H;
  int hi = min(lo + RANGE_H, N);
  int len = hi - lo;
  long base = (long)b * chunk;
  int cnt = (int)min((long)chunk, (long)E - base);
  if (cnt < 0) cnt = 0;
  int t = threadIdx.x;
  for (int i = t; i < len; i += BIG) { sc[i] = 0; sd[i] = 0.f; }
  __syncthreads();
  for (int i = t; i < cnt; i += BIG) {
    long e = base + i;
    int c = col[e], r = row[e];
    if (c >= lo && c < hi) atomicAdd(&sc[c - lo], 1);     // LDS atomic
    if (r >= lo && r < hi) atomicAdd(&sd[r - lo], w[e]);  // LDS atomic
  }
  __syncthreads();
  for (int i = t; i < len; i += BIG) {
    H[(long)b * N + lo + i] = sc[i];
    degH[(long)b * N + lo + i] = sd[i];
  }
}

// thread-per-bin: exclusive column prefix of H over blocks (coalesced), totals -> cnt,
// fused degH column-reduce -> disq
__global__ void colscan_kernel(int* __restrict__ H, const float* __restrict__ degH,
                               float* __restrict__ disq, int* __restrict__ cnt,
                               int N, int nB) {
  int c = blockIdx.x * blockDim.x + threadIdx.x;
  if (c >= N) return;
  int s = 0;
  float d = 0.f;
  for (int b = 0; b < nB; b++) {
    long idx = (long)b * N + c;
    int h = H[idx];
    H[idx] = s;       // exclusive prefix within column
    s += h;
    d += degH[idx];
  }
  cnt[c] = s;
  disq[c] = (d > 0.f) ? rsqrtf(d) : 0.f;
}

// scan stage 1 over contiguous array (8192 elems/block)
__global__ void __launch_bounds__(SB)
scan1_kernel(int* __restrict__ a, int* __restrict__ bsum, int n) {
  __shared__ int s[SB];
  int t = threadIdx.x;
  int g0 = blockIdx.x * (SB * ITEMS) + t * ITEMS;
  int v[ITEMS];
  int tot = 0;
#pragma unroll
  for (int k = 0; k < ITEMS; k++) {
    int g = g0 + k;
    int u = (g < n) ? a[g] : 0;
    v[k] = u; tot += u;
  }
  s[t] = tot;
  __syncthreads();
  for (int d = 1; d < SB; d <<= 1) {
    int u = (t >= d) ? s[t - d] : 0;
    __syncthreads();
    s[t] += u;
    __syncthreads();
  }
  int run = s[t] - tot;
#pragma unroll
  for (int k = 0; k < ITEMS; k++) {
    int g = g0 + k;
    if (g < n) a[g] = run;
    run += v[k];
  }
  if (t == SB - 1) bsum[blockIdx.x] = s[SB - 1];
}

__global__ void __launch_bounds__(SB)
scan_top_kernel(int* __restrict__ bsum, int nb) {
  __shared__ int s[SB];
  int t = threadIdx.x;
  int v = (t < nb) ? bsum[t] : 0;
  s[t] = v;
  __syncthreads();
  for (int d = 1; d < SB; d <<= 1) {
    int u = (t >= d) ? s[t - d] : 0;
    __syncthreads();
    s[t] += u;
    __syncthreads();
  }
  if (t < nb) bsum[t] = s[t] - v;
}

__global__ void scan_add_kernel(int* __restrict__ a, const int* __restrict__ bsum, int n) {
  int g = blockIdx.x * blockDim.x + threadIdx.x;
  if (g < n) a[g] += bsum[g >> 13];
}

// grid (nB, nRB): block (b,p) places chunk b's edges with col in range p.
// cursor base = starts[c] + H[b][c]; LDS atomics only.
__global__ void __launch_bounds__(BIG)
bucket2_kernel(const int* __restrict__ row, const int* __restrict__ col,
               const float* __restrict__ w, const float* __restrict__ disq,
               const int* __restrict__ H, const int* __restrict__ starts,
               int2* __restrict__ pairs, int E, int N, int chunk) {
  __shared__ int cur[RANGE_B];
  int b = blockIdx.x;
  int lo = blockIdx.y * RANGE_B;
  int hi = min(lo + RANGE_B, N);
  int len = hi - lo;
  long base = (long)b * chunk;
  int cnt = (int)min((long)chunk, (long)E - base);
  if (cnt < 0) cnt = 0;
  int t = threadIdx.x;
  for (int i = t; i < len; i += BIG)
    cur[i] = H[(long)b * N + lo + i] + starts[lo + i];
  __syncthreads();
  for (int i = t; i < cnt; i += BIG) {
    long e = base + i;
    int c = col[e];
    if (c >= lo && c < hi) {
      int r = row[e];
      float nm = -w[e] * disq[r] * disq[c];
      int pos = atomicAdd(&cur[c - lo], 1);   // LDS atomic, exclusive (b,c) ranges
      pairs[pos] = make_int2(r, __float_as_int(nm));
    }
  }
}

// ================= legacy fallback (device atomics) =================

__global__ void zero_kernel(int* __restrict__ p, long n) {
  long i = (long)blockIdx.x * blockDim.x + threadIdx.x;
  long stride = (long)gridDim.x * blockDim.x;
  for (; i < n; i += stride) p[i] = 0;
}

__global__ void deghist_dev_kernel(const float* __restrict__ w, const int* __restrict__ row,
                                   const int* __restrict__ col, float* __restrict__ deg,
                                   int* __restrict__ cntArr, int E) {
  int e = blockIdx.x * blockDim.x + threadIdx.x;
  if (e < E) {
    atomicAdd(&deg[row[e]], w[e]);
    atomicAdd(&cntArr[col[e]], 1);
  }
}

__global__ void bucket_dev_kernel(const float* __restrict__ w, const int* __restrict__ row,
                                  const int* __restrict__ col, const float* __restrict__ disq,
                                  int* __restrict__ off, int2* __restrict__ pairs, int E) {
  int e = blockIdx.x * blockDim.x + threadIdx.x;
  if (e >= E) return;
  int r = row[e], c = col[e];
  float v = -w[e] * disq[r] * disq[c];
  int p = atomicAdd(&off[c], 1);
  pairs[p] = make_int2(r, __float_as_int(v));
}

// ================= shared tail =================

// MODE 0: S[c] = start, end = S[c+1] (or E).  MODE 1: S[c] = end, start = S[c-1] (or 0).
template <int MODE>
__global__ void gather_kernel(const float* __restrict__ x, const int* __restrict__ S,
                              const int2* __restrict__ pairs, float* __restrict__ Tx,
                              int n, int E) {
  int wid = (int)(((long)blockIdx.x * blockDim.x + threadIdx.x) >> 6);
  if (wid >= n) return;
  int lane = threadIdx.x & 63;
  int slot = lane >> 3;
  int f4 = lane & 7;
  int start, end;
  if (MODE == 0) { start = S[wid]; end = (wid + 1 < n) ? S[wid + 1] : E; }
  else           { start = wid ? S[wid - 1] : 0; end = S[wid]; }
  float4 acc = make_float4(0.f, 0.f, 0.f, 0.f);
  for (int i = start + slot; i < end; i += 8) {
    int2 pv = pairs[i];
    float v = __int_as_float(pv.y);
    float4 xr = *(const float4*)(x + (long)pv.x * 32 + f4 * 4);
    acc.x += v * xr.x;
    acc.y += v * xr.y;
    acc.z += v * xr.z;
    acc.w += v * xr.w;
  }
#pragma unroll
  for (int d = 8; d < 64; d <<= 1) {
    acc.x += __shfl_xor(acc.x, d);
    acc.y += __shfl_xor(acc.y, d);
    acc.z += __shfl_xor(acc.z, d);
    acc.w += __shfl_xor(acc.w, d);
  }
  if (slot == 0) *(float4*)(Tx + (long)wid * 32 + f4 * 4) = acc;
}

__global__ void __launch_bounds__(T256, 2)
gate_kernel(const float* __restrict__ x, const float* __restrict__ Tx,
            const float* __restrict__ Wx0, const float* __restrict__ Wx1,
            const float* __restrict__ bx, const float* __restrict__ bh,
            const float* __restrict__ Wlin, const float* __restrict__ blin,
            float* __restrict__ out, int n) {
  int lane = threadIdx.x & 63;
  int wave = blockIdx.x * (T256 / 64) + (threadIdx.x >> 6);
  int nwaves = gridDim.x * (T256 / 64);

  float wz0[32], wz1[32], wt0[32], wt1[32];
#pragma unroll
  for (int f = 0; f < 32; f++) {
    wz0[f] = Wx0[f * 64 + lane];
    wz1[f] = Wx1[f * 64 + lane];
    wt0[f] = Wx0[4096 + f * 64 + lane];
    wt1[f] = Wx1[4096 + f * 64 + lane];
  }
  float bz = bx[lane] + bh[lane];
  float bt = bx[128 + lane] + bh[128 + lane];
  float wl = Wlin[lane];
  float bl = blin[0];

  for (int node = wave; node < n; node += nwaves) {
    const float4* xp = (const float4*)(x + (long)node * 32);
    const float4* tp = (const float4*)(Tx + (long)node * 32);
    float azx = 0.f, azt = 0.f, atx = 0.f, att = 0.f;
#pragma unroll
    for (int c = 0; c < 8; c++) {
      float4 xa = xp[c];
      float4 ta = tp[c];
      azx += xa.x * wz0[4 * c + 0];
      azx += xa.y * wz0[4 * c + 1];
      azx += xa.z * wz0[4 * c + 2];
      azx += xa.w * wz0[4 * c + 3];
      azt += ta.x * wz1[4 * c + 0];
      azt += ta.y * wz1[4 * c + 1];
      azt += ta.z * wz1[4 * c + 2];
      azt += ta.w * wz1[4 * c + 3];
      atx += xa.x * wt0[4 * c + 0];
      atx += xa.y * wt0[4 * c + 1];
      atx += xa.z * wt0[4 * c + 2];
      atx += xa.w * wt0[4 * c + 3];
      att += ta.x * wt1[4 * c + 0];
      att += ta.y * wt1[4 * c + 1];
      att += ta.z * wt1[4 * c + 2];
      att += ta.w * wt1[4 * c + 3];
    }
    float az = azx + azt + bz;
    float at = atx + att + bt;
    float zk = 1.0f / (1.0f + __expf(-az));
    float contrib = (1.0f - zk) * tanhf(at) * wl;
#pragma unroll
    for (int d = 1; d < 64; d <<= 1) contrib += __shfl_xor(contrib, d);
    if (lane == 0) out[node] = contrib + bl;
  }
}

extern "C" void kernel_launch(void* const* d_in, const int* in_sizes, int n_in,
                              void* d_out, int out_size, void* d_ws, size_t ws_size,
                              hipStream_t stream) {
  const float* x    = (const float*)d_in[0];
  const float* ew   = (const float*)d_in[1];
  const float* Wx0  = (const float*)d_in[2];
  const float* Wx1  = (const float*)d_in[3];
  const float* bx   = (const float*)d_in[4];
  const float* bh   = (const float*)d_in[7];
  const float* Wlin = (const float*)d_in[8];
  const float* blin = (const float*)d_in[9];
  const int*   ei   = (const int*)d_in[10];

  int N = in_sizes[0] / 32;
  int E = in_sizes[1];
  const int* row = ei;
  const int* col = ei + E;
  float* out = (float*)d_out;
  long tthreads = (long)N * 64;
  int nRH = (N + RANGE_H - 1) / RANGE_H;
  int nRB = (N + RANGE_B - 1) / RANGE_B;

  // layout: [Tx 32N][disq N][starts N][bsum 1024][H nB*N][degH∪pairs max(nB*N,2E)]
  int nBopts[5] = {85, 64, 48, 32, 16};
  int nB = 0;
  size_t wTx = (size_t)N * 32, wRegion = 0;
  for (int k = 0; k < 5; k++) {
    size_t cb = (size_t)nBopts[k];
    size_t h = cb * N;
    size_t region = h > (size_t)2 * E ? h : (size_t)2 * E;
    size_t tot = wTx + N + N + 1024 + h + region;
    if (tot * 4 <= ws_size) { nB = nBopts[k]; wRegion = region; break; }
  }

  if (nB > 0) {
    float* Tx     = (float*)d_ws;
    float* disq   = Tx + wTx;
    int*   starts = (int*)(disq + N);
    int*   bsum   = starts + N;
    int*   H      = bsum + 1024;
    float* degH   = (float*)(H + (size_t)nB * N);   // aliased with pairs (degH dead first)
    int2*  pairs  = (int2*)degH;

    int chunk = (E + nB - 1) / nB;
    int nb1 = (N + SB * ITEMS - 1) / (SB * ITEMS);

    histdeg_kernel<<<dim3(nB, nRH), BIG, 0, stream>>>(row, col, ew, H, degH, E, N, chunk);
    colscan_kernel<<<(N + T256 - 1) / T256, T256, 0, stream>>>(H, degH, disq, starts, N, nB);
    scan1_kernel<<<nb1, SB, 0, stream>>>(starts, bsum, N);
    scan_top_kernel<<<1, SB, 0, stream>>>(bsum, nb1);
    scan_add_kernel<<<(N + T256 - 1) / T256, T256, 0, stream>>>(starts, bsum, N);
    bucket2_kernel<<<dim3(nB, nRB), BIG, 0, stream>>>(row, col, ew, disq, H, starts, pairs, E, N, chunk);
    gather_kernel<0><<<(int)((tthreads + T256 - 1) / T256), T256, 0, stream>>>(
        x, starts, pairs, Tx, N, E);
    gate_kernel<<<512, T256, 0, stream>>>(x, Tx, Wx0, Wx1, bx, bh, Wlin, blin, out, N);
  } else {
    // legacy: device-scope atomics
    float* Tx     = (float*)d_ws;
    float* disq   = Tx + wTx;
    int*   starts = (int*)(disq + N);
    int*   bsum   = starts + N;
    int*   H      = bsum + 1024;                    // N counts
    float* degH   = (float*)(H + N);                // N deg
    size_t head = wTx + N + N + 1024 + N + N;
    if (head & 1) head++;
    int2* pairs = (int2*)((float*)d_ws + head);
    int nb1 = (N + SB * ITEMS - 1) / (SB * ITEMS);
    int eb = (E + T256 - 1) / T256;

    zero_kernel<<<256, T256, 0, stream>>>(H, N);
    zero_kernel<<<256, T256, 0, stream>>>((int*)degH, N);
    deghist_dev_kernel<<<eb, T256, 0, stream>>>(ew, row, col, degH, H, E);
    colscan_kernel<<<(N + T256 - 1) / T256, T256, 0, stream>>>(H, degH, disq, starts, N, 1);
    scan1_kernel<<<nb1, SB, 0, stream>>>(starts, bsum, N);
    scan_top_kernel<<<1, SB, 0, stream>>>(bsum, nb1);
    scan_add_kernel<<<(N + T256 - 1) / T256, T256, 0, stream>>>(starts, bsum, N);
    bucket_dev_kernel<<<eb, T256, 0, stream>>>(ew, row, col, disq, starts, pairs, E);
    gather_kernel<1><<<(int)((tthreads + T256 - 1) / T256), T256, 0, stream>>>(
        x, starts, pairs, Tx, N, E);
    gate_kernel<<<512, T256, 0, stream>>>(x, Tx, Wx0, Wx1, bx, bh, Wlin, blin, out, N);
  }
}